// Round 15
// baseline (79.436 us; speedup 1.0000x reference)
//
#include <hip/hip_runtime.h>

typedef unsigned long long u64;
typedef float v2f __attribute__((ext_vector_type(2)));

#define L_DIM 4096
#define B_DIM 4
#define KNN 48
#define CAP 512             // survivors/row ~88 (F~2.1%); 5.8x margin
#define INVALID_X2 1.0e30f  // encodes mask=0: d^2 ~ 1e30, never selectable
#define VALID_TH 1.0e29f
#define SLACK 8u            // ulp slack on d^2 threshold covering sqrt collisions
#define NT 256
#define NIT 4               // A-loop iterations; 4 candidates each (NT*16 = L)
#define ROWS 2

// ---- packed-f32 VOP3P helpers (CDNA: v_pk_*_f32; IEEE per half == scalar) ----
__device__ __forceinline__ v2f pk_mul(v2f a, v2f b) {
    v2f d; asm("v_pk_mul_f32 %0, %1, %2" : "=v"(d) : "v"(a), "v"(b)); return d;
}
__device__ __forceinline__ v2f pk_add(v2f a, v2f b) {
    v2f d; asm("v_pk_add_f32 %0, %1, %2" : "=v"(d) : "v"(a), "v"(b)); return d;
}
__device__ __forceinline__ v2f pk_fma(v2f a, v2f b, v2f c) {
    v2f d; asm("v_pk_fma_f32 %0, %1, %2, %3" : "=v"(d) : "v"(a), "v"(b), "v"(c)); return d;
}
__device__ __forceinline__ float min3f(float a, float b, float c) {
    float d; asm("v_min3_f32 %0, %1, %2, %3" : "=v"(d) : "v"(a), "v"(b), "v"(c)); return d;
}

// ---------------------------------------------------------------------------
// prep: SoA candidate arrays xs,ys,zs + ws = valid ? x2 : 1e30 (so one
// dwordx4 load in knn yields two aligned candidate-pairs, zero repacking);
// n_valid via one ballot + lane0 atomic per wave (single-address).
// x2 contracted-FMA chain (matches XLA:CPU fused codegen); dot(i,i) == x2(i)
// bit-exact => D[i,i] == 0 exactly.
// ---------------------------------------------------------------------------
__global__ __launch_bounds__(256) void prep_kernel(const float* __restrict__ X,
                                                   const float* __restrict__ mask,
                                                   float* __restrict__ xs,
                                                   float* __restrict__ ys,
                                                   float* __restrict__ zs,
                                                   float* __restrict__ ws,
                                                   int* __restrict__ nvalid) {
#pragma clang fp contract(off)
    int i = blockIdx.x * 256 + threadIdx.x;              // i in [0, B*L)
    const float4* X4 = (const float4*)X;                 // residue = 3 aligned float4
    float4 a = X4[3 * i];                                // ... f3(=CA x)
    float4 bb = X4[3 * i + 1];                           // f4(=CA y) f5(=CA z) ...
    float x = a.w, y = bb.x, z = bb.y;
    float x2 = __builtin_fmaf(z, z, __builtin_fmaf(y, y, x * x));
    float m = mask[i];
    xs[i] = x; ys[i] = y; zs[i] = z;
    ws[i] = (m > 0.0f) ? x2 : INVALID_X2;
    unsigned long long bal = __ballot(m > 0.0f);
    if ((threadIdx.x & 63) == 0)
        atomicAdd(&nvalid[i >> 12], (int)__popcll(bal));  // block spans one batch
}

// full ascending 64-lane bitonic sort; returns this lane's sorted value
__device__ __forceinline__ unsigned wave_sort64(unsigned sv, int lane) {
#pragma unroll
    for (int k = 2; k <= 64; k <<= 1) {
#pragma unroll
        for (int j = k >> 1; j > 0; j >>= 1) {
            unsigned o = __shfl_xor(sv, j);
            unsigned mn = min(sv, o), mx = max(sv, o);
            bool asc = ((lane & k) == 0);
            bool low = ((lane & j) == 0);
            sv = (asc == low) ? mn : mx;
        }
    }
    return sv;
}

// ---------------------------------------------------------------------------
// main: one block per 2 rows (same batch), 256 threads, 16 cands/thread.
//  A:  SoA dwordx4 loads -> 2 candidate-pairs; packed pk_fma chain per row
//      (bit-identical per half to scalar: fma(z,qz,fma(y,qy,x*qx)), w+qw,
//      fma(-2,dot,t1)); rmin via v_min3_f32 (float domain, negatives OK).
//  B:  group-of-4 minima (2 shfl_xor fminf) -> clamp->bits -> 64/row in LDS
//      -> ONE wave-sort per row (waves 0/1); lane47 = T (certified >= q48:
//      <=47 elements < q48 => <=47 group-minima < q48).
//  C:  float-domain compare d2 <= Tf (negatives survive => clamp semantics
//      preserved); exact key (sqrt_bits<<32|j) at push, clamp at push.
//  D:  rank-count in (sqrt_bits, idx) order == lax.top_k tie-break, scatter;
//      invalid row -> self-fill. 3 barriers, all LDS deps covered.
// ---------------------------------------------------------------------------
__global__ __launch_bounds__(NT) void knn_kernel(const float* __restrict__ xs,
                                                 const float* __restrict__ ys,
                                                 const float* __restrict__ zs,
                                                 const float* __restrict__ ws,
                                                 const int* __restrict__ nvalid,
                                                 float* __restrict__ dn,
                                                 float* __restrict__ ei) {
    __shared__ unsigned gmin[ROWS][64];  // group-of-4 minima (clamped bits)
    __shared__ u64 surv[ROWS][CAP];      // 8 KB
    __shared__ int cnt[ROWS];
    __shared__ unsigned Tsh[ROWS];

    const int row0 = blockIdx.x * ROWS;
    const int b = row0 >> 12;
    const int i0 = row0 & (L_DIM - 1);
    const int t = threadIdx.x;
    const int w = t >> 6, lane = t & 63;

    // degenerate batch -> both rows self-fill (block-uniform)
    if (nvalid[b] <= KNN) {
        if (w < ROWS && lane < KNN) {
            dn[(size_t)(row0 + w) * KNN + lane] = 0.0f;
            ei[(size_t)(row0 + w) * KNN + lane] = (float)(i0 + w);
        }
        return;
    }

    const size_t bo = (size_t)b * L_DIM;
    const float* xb = xs + bo; const float* yb = ys + bo;
    const float* zb = zs + bo; const float* wb = ws + bo;

    // query scalars + broadcast pairs (built once)
    const float q0w = wb[i0], q1w = wb[i0 + 1];
    const bool v0 = (q0w < VALID_TH), v1 = (q1w < VALID_TH);
    const v2f qx0 = {xb[i0], xb[i0]},     qy0 = {yb[i0], yb[i0]},
              qz0 = {zb[i0], zb[i0]},     qw0 = {q0w, q0w};
    const v2f qx1 = {xb[i0+1], xb[i0+1]}, qy1 = {yb[i0+1], yb[i0+1]},
              qz1 = {zb[i0+1], zb[i0+1]}, qw1 = {q1w, q1w};
    const v2f m2 = {-2.0f, -2.0f};

    // ---- A: 4 iters x 4 cands; packed d^2 pairs for both rows ----
    v2f d2a[NIT * 2], d2b[NIT * 2];      // [row][iter*2 + pairidx]
    float rmin0 = 3.402823466e38f, rmin1 = 3.402823466e38f;
#pragma unroll
    for (int c = 0; c < NIT; ++c) {
        int off = c * (NT * 4) + t * 4;
        float4 xv = *(const float4*)(xb + off);
        float4 yv = *(const float4*)(yb + off);
        float4 zv = *(const float4*)(zb + off);
        float4 wv = *(const float4*)(wb + off);
        v2f xlo = {xv.x, xv.y}, xhi = {xv.z, xv.w};
        v2f ylo = {yv.x, yv.y}, yhi = {yv.z, yv.w};
        v2f zlo = {zv.x, zv.y}, zhi = {zv.z, zv.w};
        v2f wlo = {wv.x, wv.y}, whi = {wv.z, wv.w};

        v2f dot0l = pk_fma(zlo, qz0, pk_fma(ylo, qy0, pk_mul(xlo, qx0)));
        v2f dot0h = pk_fma(zhi, qz0, pk_fma(yhi, qy0, pk_mul(xhi, qx0)));
        v2f dot1l = pk_fma(zlo, qz1, pk_fma(ylo, qy1, pk_mul(xlo, qx1)));
        v2f dot1h = pk_fma(zhi, qz1, pk_fma(yhi, qy1, pk_mul(xhi, qx1)));
        v2f d0l = pk_fma(m2, dot0l, pk_add(wlo, qw0));
        v2f d0h = pk_fma(m2, dot0h, pk_add(whi, qw0));
        v2f d1l = pk_fma(m2, dot1l, pk_add(wlo, qw1));
        v2f d1h = pk_fma(m2, dot1h, pk_add(whi, qw1));
        d2a[c * 2] = d0l; d2a[c * 2 + 1] = d0h;
        d2b[c * 2] = d1l; d2b[c * 2 + 1] = d1h;
        rmin0 = min3f(rmin0, d0l.x, d0l.y); rmin0 = min3f(rmin0, d0h.x, d0h.y);
        rmin1 = min3f(rmin1, d1l.x, d1l.y); rmin1 = min3f(rmin1, d1h.x, d1h.y);
    }

    // ---- B: group-of-4 minima -> clamp -> bits -> one wave-sort per row ----
    {
        float g0 = fminf(rmin0, __shfl_xor(rmin0, 1));
        g0 = fminf(g0, __shfl_xor(g0, 2));
        float g1 = fminf(rmin1, __shfl_xor(rmin1, 1));
        g1 = fminf(g1, __shfl_xor(g1, 2));
        if ((lane & 3) == 0) {
            gmin[0][(w << 4) | (lane >> 2)] = __float_as_uint(fmaxf(g0, 0.0f));
            gmin[1][(w << 4) | (lane >> 2)] = __float_as_uint(fmaxf(g1, 0.0f));
        }
    }
    if (t < ROWS) cnt[t] = 0;
    __syncthreads();                                   // S1
    if (w < ROWS) {
        unsigned sv = wave_sort64(gmin[w][lane], lane);
        if (lane == KNN - 1) Tsh[w] = sv;              // 48th-smallest group-min
    }
    __syncthreads();                                   // S2
    // float-domain thresholds; negatives (<0 <= Tf) survive as they must
    const float Tf0 = v0 ? __uint_as_float(Tsh[0] + SLACK) : -3.0e38f;
    const float Tf1 = v1 ? __uint_as_float(Tsh[1] + SLACK) : -3.0e38f;

    // ---- C: compact survivors; exact clamped-sqrt key at push time ----
#pragma unroll
    for (int c = 0; c < NIT * 2; ++c) {
        unsigned jb = (unsigned)((c >> 1) * (NT * 4) + t * 4 + (c & 1) * 2);
#pragma unroll
        for (int h = 0; h < 2; ++h) {
            float va = h ? d2a[c].y : d2a[c].x;
            float vb = h ? d2b[c].y : d2b[c].x;
            if (va <= Tf0) {
                int pos = atomicAdd(&cnt[0], 1);
                if (pos < CAP) {
                    float d = sqrtf(fmaxf(va, 0.0f));  // correctly rounded
                    surv[0][pos] = ((u64)__float_as_uint(d) << 32) | (jb + h);
                }
            }
            if (vb <= Tf1) {
                int pos = atomicAdd(&cnt[1], 1);
                if (pos < CAP) {
                    float d = sqrtf(fmaxf(vb, 0.0f));
                    surv[1][pos] = ((u64)__float_as_uint(d) << 32) | (jb + h);
                }
            }
        }
    }
    __syncthreads();                                   // S3

    // ---- D: per row, block-wide exact rank + scatter (or self-fill) ----
#pragma unroll
    for (int r = 0; r < ROWS; ++r) {
        const bool vr = r ? v1 : v0;
        float* dnrow = dn + (size_t)(row0 + r) * KNN;
        float* eirow = ei + (size_t)(row0 + r) * KNN;
        if (!vr) {                              // block-uniform branch
            if (t < KNN) { dnrow[t] = 0.0f; eirow[t] = (float)(i0 + r); }
        } else {
            int S = cnt[r]; if (S > CAP) S = CAP;
            for (int c = t; c < S; c += NT) {
                u64 key = surv[r][c];
                int rank = 0;
                for (int s = 0; s < S; ++s) rank += (surv[r][s] < key);  // bcast
                if (rank < KNN) {
                    dnrow[rank] = __uint_as_float((unsigned)(key >> 32));
                    eirow[rank] = (float)(key & 0xFFFFFFFFULL);
                }
            }
        }
    }
}

extern "C" void kernel_launch(void* const* d_in, const int* in_sizes, int n_in,
                              void* d_out, int out_size, void* d_ws, size_t ws_size,
                              hipStream_t stream) {
    const float* X = (const float*)d_in[0];
    const float* mask = (const float*)d_in[1];

    float* out = (float*)d_out;
    float* dn = out;                                   // (B,L,K) D_neighbors
    float* ei = out + (size_t)B_DIM * L_DIM * KNN;     // (B,L,K) E_idx as f32

    const size_t BL = (size_t)B_DIM * L_DIM;
    char* wsb = (char*)d_ws;
    float* xs = (float*)wsb;                           // 64 KiB each
    float* ys = (float*)(wsb + BL * 4);
    float* zs = (float*)(wsb + BL * 8);
    float* ws = (float*)(wsb + BL * 12);
    int* nv = (int*)(wsb + BL * 16);

    hipMemsetAsync(nv, 0, B_DIM * sizeof(int), stream);
    prep_kernel<<<(B_DIM * L_DIM) / 256, 256, 0, stream>>>(X, mask, xs, ys, zs, ws, nv);
    knn_kernel<<<(B_DIM * L_DIM) / ROWS, NT, 0, stream>>>(xs, ys, zs, ws, nv, dn, ei);
}